// Round 16
// baseline (129.984 us; speedup 1.0000x reference)
//
#include <hip/hip_runtime.h>
#include <hip/hip_bf16.h>
#include <math.h>

#define DD 768
#define BB 32
#define PP 512
#define TT 512
#define CC 97
#define THRESH 0.8f
#define BK 32

typedef __attribute__((ext_vector_type(8))) short short8;
typedef __attribute__((ext_vector_type(4))) float f32x4;

__device__ __forceinline__ short bfc(float x) {
    __hip_bfloat16 h = __float2bfloat16(x);
    return *(short*)&h;
}

__device__ __forceinline__ void gload16(const void* g, void* l) {
    __builtin_amdgcn_global_load_lds(
        (const __attribute__((address_space(1))) unsigned int*)g,
        (__attribute__((address_space(3))) unsigned int*)l, 16, 0, 0);
}

// ---------------- fused match: gload_lds fp32 staging + convert-on-read ------
// R16 = R8's proven HW-async pipeline (global_load_lds, counted vmcnt(8),
// STAGE->vmcnt->bar->COMPUTE->bar, 2 bufs) + R10's fusion (raw fp32 in, no
// norm prepass). fp32 tiles staged directly; frag read = 2 swizzled
// ds_read_b128 (8 fp32) + cvt->bf16 in regs; sum-of-squares accumulated from
// the SAME frag fp32 values by designated waves (qc==0 own A rows, qr==0 own
// B rows -> each value counted once). No reg-staging -> no loop-carried-reg
// waitcnt degradation (R15's flaw). Tile 128p x 128t, 8 waves, 64x64
// quadrants, acc 16 f32x4 = 64 AGPR. LDS 2 x 64KB + norms = 130KB, 1 blk/CU.
// Swizzle (both sides): content slot c of row r at phys slot c^(r&7)
// (128B fp32 rows, 8 x 16B slots); gload source pre-permuted identically.
__global__ __launch_bounds__(512, 2) void match_kernel(
        const float* __restrict__ pairs, const float* __restrict__ trip,
        float* __restrict__ cand_v, int* __restrict__ cand_t) {
    __shared__ __align__(16) char smem[131072];   // 2 x 64KB (Ah16|At16|Bh16|Bt16)
    __shared__ float norms[512];                  // [Ah128|At128|Bh128|Bt128]

    // XCD swizzle (512 blocks, %8==0 -> bijective); 16 consecutive = 1 batch
    int bid = blockIdx.x;
    int swz = (bid & 7) * 64 + (bid >> 3);
    int b = swz >> 4, sub = swz & 15;
    int pblk = sub >> 2, tblk = sub & 3;          // 4 p-blocks x 4 t-blocks

    int tid = threadIdx.x;
    int w = tid >> 6, l = tid & 63;
    int l15 = l & 15, lg = l >> 4;

    const float* pairs_b = pairs + ((size_t)b * PP + pblk * 128) * (2 * DD);
    const float* trip_b  = trip  + ((size_t)b * TT + tblk * 128) * (2 * DD + 1);

    // staging: 8 pieces/thread (4096 16B-slots: 512 rows x 8 slots).
    // piece r -> slot s = tid + 512r; row = s>>3 (pieces pair up: +64 rows),
    // slot8 = tid&7 for all pieces. source slot = slot8 ^ (row&7).
    int x = (tid & 7) ^ ((tid >> 3) & 7);         // row&7 == (tid>>3)&7 for all
    const float* sp_a = pairs_b + (size_t)(tid >> 3) * 1536 + x * 4;
    const float* sp_b = trip_b + (size_t)(tid >> 3) * 1537 + x * 4;
    int dst = tid * 16;

#define STAGE(bufb, step)                                                     \
    do {                                                                      \
        size_t ko = (size_t)(step) * BK;                                      \
        char* lb = smem + (bufb) + dst;                                       \
        gload16(sp_a + ko, lb);                  /* Ah rows 0-63   */         \
        gload16(sp_a + ko + 98304, lb + 8192);   /* Ah rows 64-127 */         \
        gload16(sp_a + ko + 768, lb + 16384);    /* At rows 0-63   */         \
        gload16(sp_a + ko + 99072, lb + 24576);  /* At rows 64-127 */         \
        gload16(sp_b + ko, lb + 32768);          /* Bh rows 0-63   */         \
        gload16(sp_b + ko + 98368, lb + 40960);  /* Bh rows 64-127 */         \
        gload16(sp_b + ko + 769, lb + 49152);    /* Bt rows 0-63   */         \
        gload16(sp_b + ko + 99137, lb + 57344);  /* Bt rows 64-127 */         \
    } while (0)

    // frag addressing: row pitch 128B; content slot 2lg+h at phys
    // (2lg+h)^(l15&7) (row&7 == l15&7 for rows qr*64+i*16+l15).
    int qi = w & 3, qr = qi >> 1, qc = qi & 1;
    int Aoff = (w < 4) ? 0 : 16384;
    int Boff = (w < 4) ? 32768 : 49152;
    int sA = ((2 * lg) ^ (l15 & 7)) * 16;
    int sB = ((2 * lg + 1) ^ (l15 & 7)) * 16;
    int Ab = Aoff + (qr * 64 + l15) * 128;        // +i*2048
    int Bb = Boff + (qc * 64 + l15) * 128;        // +j*2048
    bool doA = (qc == 0);                         // sq ownership (once/value)
    bool doB = (qr == 0);

    f32x4 c00 = {0.f,0.f,0.f,0.f}, c01 = c00, c02 = c00, c03 = c00;
    f32x4 c10 = c00, c11 = c00, c12 = c00, c13 = c00;
    f32x4 c20 = c00, c21 = c00, c22 = c00, c23 = c00;
    f32x4 c30 = c00, c31 = c00, c32 = c00, c33 = c00;
    float sqa0 = 0.f, sqa1 = 0.f, sqa2 = 0.f, sqa3 = 0.f;
    float sqb0 = 0.f, sqb1 = 0.f, sqb2 = 0.f, sqb3 = 0.f;

#define MM(i, j, fa, fb) c##i##j = __builtin_amdgcn_mfma_f32_16x16x32_bf16(fa, fb, c##i##j, 0, 0, 0)
#define FRAGA(i)                                                              \
    do {                                                                      \
        f32x4 u = *(const f32x4*)(bp + Ab + (i) * 2048 + sA);                 \
        f32x4 v = *(const f32x4*)(bp + Ab + (i) * 2048 + sB);                 \
        if (doA) sqa##i += u[0]*u[0]+u[1]*u[1]+u[2]*u[2]+u[3]*u[3]            \
                         + v[0]*v[0]+v[1]*v[1]+v[2]*v[2]+v[3]*v[3];           \
        fa##i[0]=bfc(u[0]); fa##i[1]=bfc(u[1]); fa##i[2]=bfc(u[2]);           \
        fa##i[3]=bfc(u[3]); fa##i[4]=bfc(v[0]); fa##i[5]=bfc(v[1]);           \
        fa##i[6]=bfc(v[2]); fa##i[7]=bfc(v[3]);                               \
    } while (0)
#define FRAGB(j)                                                              \
    do {                                                                      \
        f32x4 u = *(const f32x4*)(bp + Bb + (j) * 2048 + sA);                 \
        f32x4 v = *(const f32x4*)(bp + Bb + (j) * 2048 + sB);                 \
        if (doB) sqb##j += u[0]*u[0]+u[1]*u[1]+u[2]*u[2]+u[3]*u[3]            \
                         + v[0]*v[0]+v[1]*v[1]+v[2]*v[2]+v[3]*v[3];           \
        g##j[0]=bfc(u[0]); g##j[1]=bfc(u[1]); g##j[2]=bfc(u[2]);              \
        g##j[3]=bfc(u[3]); g##j[4]=bfc(v[0]); g##j[5]=bfc(v[1]);              \
        g##j[6]=bfc(v[2]); g##j[7]=bfc(v[3]);                                 \
    } while (0)
#define COMPUTE(cb)                                                           \
    do {                                                                      \
        const char* bp = smem + (cb);                                         \
        short8 fa0, fa1, fa2, fa3, g0, g1, g2, g3;                            \
        FRAGA(0); FRAGA(1); FRAGA(2); FRAGA(3);                               \
        FRAGB(0); FRAGB(1); FRAGB(2); FRAGB(3);                               \
        __builtin_amdgcn_s_setprio(1);                                        \
        MM(0,0,fa0,g0); MM(1,0,fa1,g0); MM(2,0,fa2,g0); MM(3,0,fa3,g0);       \
        MM(0,1,fa0,g1); MM(1,1,fa1,g1); MM(2,1,fa2,g1); MM(3,1,fa3,g1);       \
        MM(0,2,fa0,g2); MM(1,2,fa1,g2); MM(2,2,fa2,g2); MM(3,2,fa3,g2);       \
        MM(0,3,fa0,g3); MM(1,3,fa1,g3); MM(2,3,fa2,g3); MM(3,3,fa3,g3);       \
        __builtin_amdgcn_s_setprio(0);                                        \
    } while (0)

    STAGE(0, 0);
    for (int t = 0; t < 23; ++t) {
        STAGE(((t + 1) & 1) * 65536, t + 1);
        asm volatile("s_waitcnt vmcnt(8)" ::: "memory");
        __builtin_amdgcn_s_barrier();
        asm volatile("" ::: "memory");
        COMPUTE((t & 1) * 65536);
        asm volatile("" ::: "memory");
        __builtin_amdgcn_s_barrier();
    }
    asm volatile("s_waitcnt vmcnt(0)" ::: "memory");
    __builtin_amdgcn_s_barrier();
    asm volatile("" ::: "memory");
    COMPUTE(65536);                               // t = 23 (buf 1)
#undef COMPUTE
#undef FRAGA
#undef FRAGB
#undef MM
#undef STAGE

    __syncthreads();
    // finalize norms: reduce each sq over the 4 lg groups (lanes share l15)
#define RED(s) { s += __shfl_xor(s, 16); s += __shfl_xor(s, 32); }
    RED(sqa0) RED(sqa1) RED(sqa2) RED(sqa3)
    RED(sqb0) RED(sqb1) RED(sqb2) RED(sqb3)
#undef RED
    if (lg == 0) {
        if (doA) {                                // H->Ah, T->At
            int base = (w < 4) ? 0 : 128;
            norms[base + qr * 64 + 0 * 16 + l15] = sqa0;
            norms[base + qr * 64 + 1 * 16 + l15] = sqa1;
            norms[base + qr * 64 + 2 * 16 + l15] = sqa2;
            norms[base + qr * 64 + 3 * 16 + l15] = sqa3;
        }
        if (doB) {                                // H->Bh, T->Bt
            int base = (w < 4) ? 256 : 384;
            norms[base + qc * 64 + 0 * 16 + l15] = sqb0;
            norms[base + qc * 64 + 1 * 16 + l15] = sqb1;
            norms[base + qc * 64 + 2 * 16 + l15] = sqb2;
            norms[base + qc * 64 + 3 * 16 + l15] = sqb3;
        }
    }
    __syncthreads();

    // scale raw dots -> cosines: c[i][j][r] *= rsqrt(nA[p]) * rsqrt(nB[t])
    {
        const float* nA = norms + ((w < 4) ? 0 : 128);
        const float* nB = norms + ((w < 4) ? 256 : 384);
        float ivB0 = rsqrtf(nB[qc * 64 + 0 * 16 + l15]);
        float ivB1 = rsqrtf(nB[qc * 64 + 1 * 16 + l15]);
        float ivB2 = rsqrtf(nB[qc * 64 + 2 * 16 + l15]);
        float ivB3 = rsqrtf(nB[qc * 64 + 3 * 16 + l15]);
#define SCJ(ii, jj) { c##ii##jj[0] *= s0 * ivB##jj; c##ii##jj[1] *= s1 * ivB##jj; \
                      c##ii##jj[2] *= s2 * ivB##jj; c##ii##jj[3] *= s3 * ivB##jj; }
#define SCA(ii) { float s0 = rsqrtf(nA[qr * 64 + ii * 16 + lg * 4 + 0]);      \
                  float s1 = rsqrtf(nA[qr * 64 + ii * 16 + lg * 4 + 1]);      \
                  float s2 = rsqrtf(nA[qr * 64 + ii * 16 + lg * 4 + 2]);      \
                  float s3 = rsqrtf(nA[qr * 64 + ii * 16 + lg * 4 + 3]);      \
                  SCJ(ii,0) SCJ(ii,1) SCJ(ii,2) SCJ(ii,3) }
        SCA(0) SCA(1) SCA(2) SCA(3)
#undef SCA
#undef SCJ
    }
    __syncthreads();

    // epilogue (R7/R12-verified): H-wave wp + T-wave wp, swizzled quad exchange.
    float* bwv = (float*)(smem + 16384);          // [128][2]
    int*   bwt = (int*)(smem + 17408);            // [128][2]
    int wp = w & 3;
    char* xrow = smem + (wp * 64 + l) * 64;       // 16KB exchange region
    int qsw = (l >> 1) & 3;

#define XW(q, v) *(f32x4*)(xrow + (((q) ^ qsw) * 16)) = (v)
#define XR(q)    *(const f32x4*)(xrow + (((q) ^ qsw) * 16))

#define ASTEP(ii, jj, rr, TQ)                                                 \
        { float h = c##ii##jj[rr]; float tv = (TQ)[rr];                       \
          bool ok = (h > THRESH) && (tv > THRESH);                            \
          float sc = ok ? 0.5f * (h + tv) : -INFINITY;                        \
          if (sc > bv) { bv = sc; bt = qc * 64 + jj * 16 + l15; } }

#define AMX(ii, rr)                                                           \
    {   float bv = -INFINITY; int bt = 0x7fffffff;                            \
        ASTEP(ii, 0, rr, t0) ASTEP(ii, 1, rr, t1)                             \
        ASTEP(ii, 2, rr, t2) ASTEP(ii, 3, rr, t3)                             \
        for (int m = 1; m < 16; m <<= 1) {                                    \
            float v2 = __shfl_xor(bv, m); int q2 = __shfl_xor(bt, m);         \
            if (v2 > bv || (v2 == bv && q2 < bt)) { bv = v2; bt = q2; }       \
        }                                                                     \
        if (l15 == 0) { int p = qr * 64 + ii * 16 + lg * 4 + rr;              \
            bwv[p * 2 + qc] = bv; bwt[p * 2 + qc] = bt; }                     \
    }

#define EPI(ii)                                                               \
    if (w >= 4) { XW(0, c##ii##0); XW(1, c##ii##1);                           \
                  XW(2, c##ii##2); XW(3, c##ii##3); }                         \
    __syncthreads();                                                          \
    if (w < 4) {                                                              \
        f32x4 t0 = XR(0), t1 = XR(1), t2 = XR(2), t3 = XR(3);                 \
        AMX(ii, 0) AMX(ii, 1) AMX(ii, 2) AMX(ii, 3)                           \
    }                                                                         \
    __syncthreads();

    EPI(0)
    EPI(1)
    EPI(2)
    EPI(3)
#undef EPI
#undef AMX
#undef ASTEP
#undef XW
#undef XR

    if (tid < 128) {
        float v = bwv[tid * 2 + 0]; int t1 = bwt[tid * 2 + 0];
        float v2 = bwv[tid * 2 + 1]; int t2 = bwt[tid * 2 + 1];
        if (v2 > v || (v2 == v && t2 < t1)) { v = v2; t1 = t2; }
        int grow = b * PP + pblk * 128 + tid;
        cand_v[(size_t)grow * 4 + tblk] = v;
        cand_t[(size_t)grow * 4 + tblk] = (v > -INFINITY) ? (tblk * 128 + t1) : 0x7fffffff;
    }
}

// ---------------- stage 3: fused merge + per-row NLL -------------------------
__global__ void nll_kernel(const float* __restrict__ preds,
                           const float* __restrict__ cand_v,
                           const int* __restrict__ cand_t,
                           const float* __restrict__ trip,
                           float* __restrict__ partials) {
    int w = threadIdx.x >> 6, l = threadIdx.x & 63;
    int row = blockIdx.x * 4 + w;
    const float* x = preds + (size_t)row * CC;

    float v = (l < 4) ? cand_v[(size_t)row * 4 + l] : -INFINITY;
    int  tt = (l < 4) ? cand_t[(size_t)row * 4 + l] : 0x7fffffff;
#pragma unroll
    for (int m = 1; m < 4; m <<= 1) {
        float v2 = __shfl_xor(v, m); int t2 = __shfl_xor(tt, m);
        if (v2 > v || (v2 == v && t2 < tt)) { v = v2; tt = t2; }
    }
    int bb = row >> 9;
    int tg = 0;
    if (l == 0 && v > -INFINITY)
        tg = (int)trip[((size_t)bb * TT + tt) * (2 * DD + 1) + DD];
    tg = __shfl(tg, 0);

    float a = x[l];
    float b2 = (l + 64 < CC) ? x[l + 64] : -INFINITY;
    float mx = fmaxf(a, b2);
    for (int m = 32; m; m >>= 1) mx = fmaxf(mx, __shfl_xor(mx, m));
    float e = __expf(a - mx) + ((l + 64 < CC) ? __expf(b2 - mx) : 0.0f);
    for (int m = 32; m; m >>= 1) e += __shfl_xor(e, m);

    __shared__ float part[4];
    if (l == 0) part[w] = mx + logf(e) - x[tg];
    __syncthreads();
    if (threadIdx.x == 0)
        partials[blockIdx.x] = part[0] + part[1] + part[2] + part[3];
}

// ---------------- stage 4: final mean ----------------------------------------
__global__ void final_reduce_kernel(const float* __restrict__ partials, int n,
                                    float* __restrict__ out) {
    float s = 0.f;
    for (int i = threadIdx.x; i < n; i += 256) s += partials[i];
    for (int m = 32; m; m >>= 1) s += __shfl_xor(s, m);
    __shared__ float ps[4];
    if ((threadIdx.x & 63) == 0) ps[threadIdx.x >> 6] = s;
    __syncthreads();
    if (threadIdx.x == 0)
        out[0] = (ps[0] + ps[1] + ps[2] + ps[3]) / (float)(BB * PP);
}

extern "C" void kernel_launch(void* const* d_in, const int* in_sizes, int n_in,
                              void* d_out, int out_size, void* d_ws, size_t ws_size,
                              hipStream_t stream) {
    const float* pairs = (const float*)d_in[0];  // [B,P,1536]
    const float* preds = (const float*)d_in[1];  // [B,P,97]
    const float* trip  = (const float*)d_in[2];  // [B,T,1537]
    float* out = (float*)d_out;

    char* p = (char*)d_ws;
    float* cand_v = (float*)p;       p += (size_t)BB * PP * 4 * sizeof(float);  // 256KB
    int* cand_t = (int*)p;           p += (size_t)BB * PP * 4 * sizeof(int);    // 256KB
    float* partials = (float*)p;                                                // 16KB

    match_kernel<<<BB * 16, 512, 0, stream>>>(pairs, trip, cand_v, cand_t);
    nll_kernel<<<BB * PP / 4, 256, 0, stream>>>(preds, cand_v, cand_t, trip, partials);
    final_reduce_kernel<<<1, 256, 0, stream>>>(partials, BB * PP / 4, out);
}